// Round 7
// baseline (495.287 us; speedup 1.0000x reference)
//
#include <hip/hip_runtime.h>

// MPS encoder, R6b: VECTOR-chain redesign (no segmentation, no matrix products).
// Fix vs R6: __fp16 vector type for cvt_pkrtz/fdot2 (gfx950 builtin type);
// MBAT 2056->2064 and RESBAT 68->80 so all uint4 LDS reads are 16B-aligned.
// Per site: build M (fp8 MFMA, verified math) -> fp16 LDS (true scale, s=1/16
// cancels core8's x16), fold res_new[r] = sum_d res[d]*M[d][r] via
// v_dot2_f32_f16 (fp32 accum), res repacked as fp16 pairs (wave-local).
// 1 barrier/site, double-buffered M. Grid = 128 blocks x 512 thr (16 batch/blk).

#define NSITES 128
#define FEATD  64
#define BOND   32
#define OUTD   256
#define BT     16
#define NBLK   (2048 / BT)   // 128

#define MBAT   2064                      // batch stride in M buffer (16-aligned)
#define MBUF   (BT * MBAT)               // 33024 (one site buffer)
#define RESOFF (2 * MBUF)                // 66048
#define RESBAT 80                        // 64B res + pad, 16-aligned
#define VALOFF (RESOFF + BT * RESBAT)    // 67328
#define LDSSZ  (VALOFF + 64)             // 67392

typedef __attribute__((ext_vector_type(4))) float float4v;
typedef __fp16 h2 __attribute__((ext_vector_type(2)));

union h2u { h2 h; unsigned u; };

__device__ __forceinline__ unsigned pkrtz(float a, float b) {
    h2u v; v.h = __builtin_amdgcn_cvt_pkrtz(a, b); return v.u;
}
__device__ __forceinline__ float dot2(unsigned a, unsigned b, float acc) {
    h2u x, y; x.u = a; y.u = b;
    return __builtin_amdgcn_fdot2(x.h, y.h, acc, false);
}
__device__ __forceinline__ unsigned pk4_fp8(float a, float b, float c, float d) {
    int v = __builtin_amdgcn_cvt_pk_fp8_f32(a, b, 0, false);
    v = __builtin_amdgcn_cvt_pk_fp8_f32(c, d, v, true);
    return (unsigned)v;
}
__device__ __forceinline__ long mk64(unsigned lo, unsigned hi) {
    return (long)(((unsigned long long)hi << 32) | lo);
}

// x B-fragment: lane (cl,q) loads batch b0+cl, feats q*8..+7 and 32+q*8..+7
// (same verified lane mapping as R0-R5).
__device__ __forceinline__ void xcvt2(const float* xl, int n, long& o0, long& o1) {
    const float* p = xl + (size_t)n * FEATD;
    float4 a = *(const float4*)p,        b = *(const float4*)(p + 4);
    float4 c = *(const float4*)(p + 32), d = *(const float4*)(p + 36);
    o0 = mk64(pk4_fp8(a.x, a.y, a.z, a.w), pk4_fp8(b.x, b.y, b.z, b.w));
    o1 = mk64(pk4_fp8(c.x, c.y, c.z, c.w), pk4_fp8(d.x, d.y, d.z, d.w));
}

// core fragments (A-operand), core8 layout c' = r*32+d (prep below).
#define AF_LOAD(A, s_) { const unsigned char* p_ = cb + (size_t)(s_) * 65536; \
    _Pragma("unroll") for (int i_ = 0; i_ < 8; ++i_) { \
        (A)[2*i_+0] = *(const long*)(p_ + i_*1024); \
        (A)[2*i_+1] = *(const long*)(p_ + i_*1024 + 32); } }

// build site -> M fp16 rows (row r holds M[d][r] for all d), 16B-chunk XOR
// swizzle by (r&3). acc[i][g] = 16*M at c' = wave*128 + i*16 + 4q + g, i.e.
// r = wave*4 + (i>>1), d = (i&1)*16 + 4q + g, batch = cl. s=1/16 -> true M.
__device__ __forceinline__ void build_pack(const long af[16], long bx0, long bx1,
                                           unsigned char* Mw, int wbase,
                                           int qb0, int qb1) {
    float4v acc[8];
#pragma unroll
    for (int i = 0; i < 8; ++i) {
        float4v z = {0.f, 0.f, 0.f, 0.f};
        z = __builtin_amdgcn_mfma_f32_16x16x32_fp8_fp8(af[2*i+0], bx0, z, 0, 0, 0);
        acc[i] = __builtin_amdgcn_mfma_f32_16x16x32_fp8_fp8(af[2*i+1], bx1, z, 0, 0, 0);
    }
    const float s = 0.0625f;   // exact /16 (power of 2): stored M = true M
#pragma unroll
    for (int i = 0; i < 8; ++i) {
        unsigned d0 = pkrtz(acc[i][0] * s, acc[i][1] * s);
        unsigned d1 = pkrtz(acc[i][2] * s, acc[i][3] * s);
        // physical chunk = logical chunk XOR (r&3):
        //   chunk bit1 = (i&1) ^ ((i>>2)&1) [imm]; bit0 = (q>>1) ^ ((i>>1)&1)
        int addr = wbase + (i >> 1) * 64 + (((i & 1) ^ ((i >> 2) & 1)) << 5)
                 + (((i >> 1) & 1) ? qb1 : qb0);
        *(unsigned long long*)&Mw[addr] = ((unsigned long long)d1 << 32) | d0;
    }
}

// fold one site: res_new[r] = sum_d res16[d] * M16[d][r]  (fp32 accum)
__device__ __forceinline__ float fold_site(const unsigned char* L, const int aM[4],
                                           int moff, int aR) {
    uint4 m0 = *(const uint4*)(L + aM[0] + moff);
    uint4 m1 = *(const uint4*)(L + aM[1] + moff);
    uint4 m2 = *(const uint4*)(L + aM[2] + moff);
    uint4 m3 = *(const uint4*)(L + aM[3] + moff);
    uint4 r0 = *(const uint4*)(L + aR);        // broadcast (same addr per half-wave)
    uint4 r1 = *(const uint4*)(L + aR + 16);
    uint4 r2 = *(const uint4*)(L + aR + 32);
    uint4 r3 = *(const uint4*)(L + aR + 48);
    float a = 0.f, b = 0.f;
    a = dot2(r0.x, m0.x, a); b = dot2(r0.y, m0.y, b);
    a = dot2(r0.z, m0.z, a); b = dot2(r0.w, m0.w, b);
    a = dot2(r1.x, m1.x, a); b = dot2(r1.y, m1.y, b);
    a = dot2(r1.z, m1.z, a); b = dot2(r1.w, m1.w, b);
    a = dot2(r2.x, m2.x, a); b = dot2(r2.y, m2.y, b);
    a = dot2(r2.z, m2.z, a); b = dot2(r2.w, m2.w, b);
    a = dot2(r3.x, m3.x, a); b = dot2(r3.y, m3.y, b);
    a = dot2(r3.z, m3.z, a); b = dot2(r3.w, m3.w, b);
    return a + b;
}

// cores [n][d][f][r] fp32 -> core8 [n][c'=r*32+d][f] fp8 (x16), LDS transpose.
__global__ __launch_bounds__(256)
void prep_cores8(const float* __restrict__ cores, unsigned char* __restrict__ core8) {
    __shared__ float tile[FEATD][BOND + 4];
    const int nd = blockIdx.x;            // n*32 + d
    const int t  = threadIdx.x;
    const float* src = cores + (size_t)nd * (FEATD * BOND);
    {
        int base = t * 8;
        int f = base >> 5, r0 = base & 31;
        float4 v0 = *(const float4*)(src + base);
        float4 v1 = *(const float4*)(src + base + 4);
        tile[f][r0 + 0] = v0.x; tile[f][r0 + 1] = v0.y;
        tile[f][r0 + 2] = v0.z; tile[f][r0 + 3] = v0.w;
        tile[f][r0 + 4] = v1.x; tile[f][r0 + 5] = v1.y;
        tile[f][r0 + 6] = v1.z; tile[f][r0 + 7] = v1.w;
    }
    __syncthreads();
    const int rr = t >> 3, f0 = (t & 7) * 8;
    const float s = 16.0f;
    unsigned lo = pk4_fp8(tile[f0 + 0][rr] * s, tile[f0 + 1][rr] * s,
                          tile[f0 + 2][rr] * s, tile[f0 + 3][rr] * s);
    unsigned hi = pk4_fp8(tile[f0 + 4][rr] * s, tile[f0 + 5][rr] * s,
                          tile[f0 + 6][rr] * s, tile[f0 + 7][rr] * s);
    uint2 w; w.x = lo; w.y = hi;
    // c' = r*32 + d  (n = nd>>5, d = nd&31)
    *(uint2*)(core8 + (((size_t)(nd >> 5) * 1024) + (size_t)rr * 32 + (nd & 31)) * 64 + f0) = w;
}

__global__ __launch_bounds__(512, 2)
void mps_vec(const float* __restrict__ x, const unsigned char* __restrict__ core8,
             const float* __restrict__ startv, const float* __restrict__ endv,
             const float* __restrict__ fc_w, const float* __restrict__ fc_b,
             float* __restrict__ out) {
    __shared__ __align__(16) unsigned char L[LDSSZ];
    const int t = threadIdx.x, wave = t >> 6, lane = t & 63;
    const int cl = lane & 15, q = lane >> 4;
    const int h = lane >> 5, r = lane & 31;
    const int b0 = blockIdx.x * BT;
    const int myb = wave * 2 + h;          // batch owned by this lane in fold

    // res init: fp16-pair copies of start, one per batch
    if (t < 256) {
        int bb = t >> 4, j = t & 15;
        *(unsigned*)&L[RESOFF + bb * RESBAT + j * 4] = pkrtz(startv[2*j], startv[2*j+1]);
    }

    // build write addressing (all imm-foldable per i)
    const int wbase = cl * MBAT + wave * 256 + (q & 1) * 8;
    const int qb0 = (q >> 1) << 4, qb1 = ((q >> 1) ^ 1) << 4;

    // fold read addressing (loop-invariant); uint4 reads all 16B-aligned
    int aM[4];
#pragma unroll
    for (int c = 0; c < 4; ++c)
        aM[c] = myb * MBAT + r * 64 + ((c ^ (r & 3)) << 4);
    const int aR  = RESOFF + myb * RESBAT;
    const int aRW = aR + (r >> 1) * 4;

    const float ev = endv[r];

    const unsigned char* cb = core8 + (size_t)(wave * 8192 + cl * 64 + q * 8);
    const float* xl = x + (size_t)(b0 + cl) * NSITES * FEATD + q * 8;

    long afA[16], afB[16];
    long xA0, xA1, xB0, xB1;

    // prologue: build site 0 -> buf0; prefetch site 1 operands
    AF_LOAD(afA, 0); xcvt2(xl, 0, xA0, xA1);
    build_pack(afA, xA0, xA1, &L[0], wbase, qb0, qb1);
    AF_LOAD(afB, 1); xcvt2(xl, 1, xB0, xB1);
    __syncthreads();   // M(0) + res init visible

    float rn = 0.f;
    for (int j = 0; j < NSITES / 2; ++j) {          // unroll x2: parities static
        const int n = 2 * j;
        // ---- interval A: build(n+1)->buf1 | fold(n) from buf0 | prefetch n+2
        {
            build_pack(afB, xB0, xB1, &L[MBUF], wbase, qb0, qb1);
            const int np = (n + 2 < NSITES) ? n + 2 : NSITES - 1;
            AF_LOAD(afA, np); xcvt2(xl, np, xA0, xA1);
            rn = fold_site(L, aM, 0, aR);
            float pt = __shfl_xor(rn, 1);
            if (!(r & 1)) *(unsigned*)&L[aRW] = pkrtz(rn, pt);
            __syncthreads();
        }
        // ---- interval B: build(n+2)->buf0 | fold(n+1) from buf1 | prefetch n+3
        {
            if (j < NSITES / 2 - 1) {
                build_pack(afA, xA0, xA1, &L[0], wbase, qb0, qb1);
                const int np = (n + 3 < NSITES) ? n + 3 : NSITES - 1;
                AF_LOAD(afB, np); xcvt2(xl, np, xB0, xB1);
            }
            rn = fold_site(L, aM, MBUF, aR);
            float pt = __shfl_xor(rn, 1);
            if (!(r & 1)) *(unsigned*)&L[aRW] = pkrtz(rn, pt);
            __syncthreads();
        }
    }

    // epilogue: val[b] = res . end ; out[b,:] = val*fc_w + fc_b   (fused)
    float prod = rn * ev;
#pragma unroll
    for (int off = 16; off >= 1; off >>= 1) prod += __shfl_down(prod, off, 32);
    if (r == 0) *(float*)&L[VALOFF + myb * 4] = prod;
    __syncthreads();
    {
        const float v = *(const float*)&L[VALOFF + (t >> 5) * 4];
        const int j0 = (t & 31) * 8;
        const int ob = b0 + (t >> 5);
#pragma unroll
        for (int i = 0; i < 2; ++i) {
            int jj = j0 + i * 4;
            float4 w4  = *(const float4*)(fc_w + jj);
            float4 bbv = *(const float4*)(fc_b + jj);
            float4 o;
            o.x = v * w4.x + bbv.x;
            o.y = v * w4.y + bbv.y;
            o.z = v * w4.z + bbv.z;
            o.w = v * w4.w + bbv.w;
            *(float4*)(out + (size_t)ob * OUTD + jj) = o;
        }
    }
}

extern "C" void kernel_launch(void* const* d_in, const int* in_sizes, int n_in,
                              void* d_out, int out_size, void* d_ws, size_t ws_size,
                              hipStream_t stream) {
    const float* x      = (const float*)d_in[0];
    const float* cores  = (const float*)d_in[1];
    const float* startv = (const float*)d_in[2];
    const float* endv   = (const float*)d_in[3];
    const float* fc_w   = (const float*)d_in[4];
    const float* fc_b   = (const float*)d_in[5];
    float* out = (float*)d_out;

    unsigned char* core8 = (unsigned char*)d_ws;   // 8.4 MB (only workspace user)

    prep_cores8<<<NSITES * BOND, 256, 0, stream>>>(cores, core8);
    mps_vec<<<NBLK, 512, 0, stream>>>(x, core8, startv, endv, fc_w, fc_b, out);
}

// Round 8
// 258.382 us; speedup vs baseline: 1.9169x; 1.9169x over previous
//
#include <hip/hip_runtime.h>

// MPS encoder, segmented-chain, pairwise folding, register-resident chain.
// R8: R4 byte-identical EXCEPT __launch_bounds__(512,2). Evidence (R7):
// VGPR_Count=56 with 64 regs of declared prefetch state => the compiler has
// been SINKING the af "prefetch" loads to their use point in every round
// (R0-R4 all VGPR=64 with afa[16]=32 regs declared). At (512,2) the budget is
// 256 VGPR/wave: afa/afb can stay resident across the interval, making the
// cross-interval core8 prefetch real. Occupancy drops to 1 block/CU -- shown
// irrelevant by R0-R4 (40% vs 54% occupancy, identical 138us).
// Scaling: core8 = fp8(16*core); frags hold 16*true values; combine /16 per seg.

#define NSITES 128
#define FEATD  64
#define BOND   32
#define OUTD   256
#define BT     16
#define SEGLEN 16
#define NSEG   (NSITES / SEGLEN)   // 8
#define NPAIR  (SEGLEN / 2)        // 8
#define NBT    (2048 / BT)         // 128

// Row stride 36 (32B + 4 pad): b64-style reads hit banks 9*cl+2q -> <=2-way.
// Batch stride 1164 = 32*36+12: /4 == 3 (mod 32) -> writes <=2-way.
#define RSTRIDE 36
#define BSTRIDE 1164
#define MSIZE   (BT * BSTRIDE)     // 18624 bytes: one M buffer

typedef __attribute__((ext_vector_type(4))) float float4v;

__device__ __forceinline__ unsigned pk4_fp8(float a, float b, float c, float d) {
    int v = __builtin_amdgcn_cvt_pk_fp8_f32(a, b, 0, false);
    v = __builtin_amdgcn_cvt_pk_fp8_f32(c, d, v, true);
    return (unsigned)v;
}

// 8-byte LDS load as two dwords (addresses only 4-aligned with RSTRIDE 36).
__device__ __forceinline__ long ld8(const unsigned char* p) {
    unsigned lo = *(const unsigned*)p;
    unsigned hi = *(const unsigned*)(p + 4);
    return (long)(((unsigned long long)hi << 32) | (unsigned long long)lo);
}

// core fragment loads for one site (A-operand of the build MFMAs). XCD-L2-hot.
__device__ __forceinline__ void af_load(long af[16], const unsigned char* __restrict__ core8,
                                        int n, int wave, int cl, int q) {
    const unsigned char* base = core8 + (size_t)n * (1024 * FEATD);
#pragma unroll
    for (int i = 0; i < 8; ++i) {
        const unsigned char* p = base + (size_t)((wave * 8 + i) * 16 + cl) * FEATD + q * 8;
        af[2 * i + 0] = *(const long*)p;
        af[2 * i + 1] = *(const long*)(p + 32);
    }
}

// Convert an MFMA D-pair (I=0 block c0, I=1 block c1 of one J-column) into an
// A/B-operand fragment, in-register (x 1/16 scale). Lane (cl,q) byte j holds
// value at m = 8q+j: reg g=(m&3) of lane (cl + 16*((m>>2)&3)), block I=m>>4.
__device__ __forceinline__ long cvt_frag(float4v c0, float4v c1,
                                         int idxlo, int idxhi, int selhi) {
    const float s = 0.0625f;
    int d0 = (int)pk4_fp8(c0[0] * s, c0[1] * s, c0[2] * s, c0[3] * s);
    int d1 = (int)pk4_fp8(c1[0] * s, c1[1] * s, c1[2] * s, c1[3] * s);
    int l0 = __builtin_amdgcn_ds_bpermute(idxlo, d0);
    int l1 = __builtin_amdgcn_ds_bpermute(idxlo, d1);
    int h0 = __builtin_amdgcn_ds_bpermute(idxhi, d0);
    int h1 = __builtin_amdgcn_ds_bpermute(idxhi, d1);
    unsigned lo = (unsigned)(selhi ? l1 : l0);
    unsigned hi = (unsigned)(selhi ? h1 : h0);
    return (long)(((unsigned long long)hi << 32) | (unsigned long long)lo);
}

// build site -> MA (d-major): row d = wave*4+(i>>1), cols r = (i&1)*16+4q+g
__device__ __forceinline__ void build_a(const long af[16], const unsigned char* xs,
                                        unsigned char* MA, int wave, int cl, int q) {
    long bx0 = *(const long*)(xs + cl * 72 + q * 8);
    long bx1 = *(const long*)(xs + cl * 72 + 32 + q * 8);
    float4v acc[8];
#pragma unroll
    for (int i = 0; i < 8; ++i) {
        float4v z = {0.f, 0.f, 0.f, 0.f};
        z = __builtin_amdgcn_mfma_f32_16x16x32_fp8_fp8(af[2 * i + 0], bx0, z, 0, 0, 0);
        acc[i] = __builtin_amdgcn_mfma_f32_16x16x32_fp8_fp8(af[2 * i + 1], bx1, z, 0, 0, 0);
    }
#pragma unroll
    for (int i = 0; i < 8; ++i) {
        unsigned w = pk4_fp8(acc[i][0], acc[i][1], acc[i][2], acc[i][3]);
        *(unsigned*)&MA[cl * BSTRIDE + (wave * 4 + (i >> 1)) * RSTRIDE
                        + (i & 1) * 16 + q * 4] = w;
    }
}

// build site -> MB (r-major): row r = 16p+4q+g, cols d = wave*4+u (pack u)
__device__ __forceinline__ void build_b(const long af[16], const unsigned char* xs,
                                        unsigned char* MB, int wave, int cl, int q) {
    long bx0 = *(const long*)(xs + cl * 72 + q * 8);
    long bx1 = *(const long*)(xs + cl * 72 + 32 + q * 8);
    float4v acc[8];
#pragma unroll
    for (int i = 0; i < 8; ++i) {
        float4v z = {0.f, 0.f, 0.f, 0.f};
        z = __builtin_amdgcn_mfma_f32_16x16x32_fp8_fp8(af[2 * i + 0], bx0, z, 0, 0, 0);
        acc[i] = __builtin_amdgcn_mfma_f32_16x16x32_fp8_fp8(af[2 * i + 1], bx1, z, 0, 0, 0);
    }
#pragma unroll
    for (int p = 0; p < 2; ++p)
#pragma unroll
        for (int g = 0; g < 4; ++g) {
            unsigned w = pk4_fp8(acc[0 + p][g], acc[2 + p][g],
                                 acc[4 + p][g], acc[6 + p][g]);
            *(unsigned*)&MB[cl * BSTRIDE + (16 * p + 4 * q + g) * RSTRIDE + wave * 4] = w;
        }
}

// cores [n][d][f][r] fp32 -> core8 [n][c=d*32+r][f] fp8 (x16), LDS transpose.
__global__ __launch_bounds__(256)
void prep_cores8(const float* __restrict__ cores, unsigned char* __restrict__ core8) {
    __shared__ float tile[FEATD][BOND + 4];
    const int nd = blockIdx.x;            // n*32 + d
    const int t  = threadIdx.x;
    const float* src = cores + (size_t)nd * (FEATD * BOND);
    {   // coalesced read of the 64x32 fp32 tile (flat = f*32 + r)
        int base = t * 8;
        int f = base >> 5, r0 = base & 31;
        float4 v0 = *(const float4*)(src + base);
        float4 v1 = *(const float4*)(src + base + 4);
        tile[f][r0 + 0] = v0.x; tile[f][r0 + 1] = v0.y;
        tile[f][r0 + 2] = v0.z; tile[f][r0 + 3] = v0.w;
        tile[f][r0 + 4] = v1.x; tile[f][r0 + 5] = v1.y;
        tile[f][r0 + 6] = v1.z; tile[f][r0 + 7] = v1.w;
    }
    __syncthreads();
    const int r = t >> 3, f0 = (t & 7) * 8;
    const float s = 16.0f;
    unsigned lo = pk4_fp8(tile[f0 + 0][r] * s, tile[f0 + 1][r] * s,
                          tile[f0 + 2][r] * s, tile[f0 + 3][r] * s);
    unsigned hi = pk4_fp8(tile[f0 + 4][r] * s, tile[f0 + 5][r] * s,
                          tile[f0 + 6][r] * s, tile[f0 + 7][r] * s);
    uint2 w; w.x = lo; w.y = hi;
    *(uint2*)(core8 + ((size_t)nd * BOND + r) * FEATD + f0) = w;
}

__global__ __launch_bounds__(512, 2)
void mps_seg(const float* __restrict__ x, const unsigned char* __restrict__ core8,
             unsigned char* __restrict__ Pout) {
    // BUF[p] = { MA (d-major) | MB (r-major) } for pair with parity p
    __shared__ __align__(16) unsigned char BUF[2][2 * MSIZE];
    __shared__ __align__(16) unsigned char XS[2][2][BT * 72];  // [pair parity][site][b][f]

    const int t    = threadIdx.x;
    const int wave = t >> 6;
    const int lane = t & 63;
    const int cl   = lane & 15;
    const int q    = lane >> 4;
    const int seg  = blockIdx.x;          // seg == XCD (% 8 round-robin)
    const int bt   = blockIdx.y;
    const int b0   = bt * BT;
    const int xb   = t >> 5, xf = (t & 31) * 2;

    const int idxlo = (cl + 16 * ((2 * q) & 3)) << 2;
    const int idxhi = (cl + 16 * ((2 * q + 1) & 3)) << 2;
    const int selhi = q >> 1;

    // running product P (= 16*identity) as B-fragments, per wave's 2 batches
    long ps[2][2];
#pragma unroll
    for (int J = 0; J < 2; ++J) {
        int row = J * 16 + cl;
        int jj  = row - 8 * q;
        long v  = (jj >= 0 && jj < 8) ? (long)(0x58ULL << (8 * jj)) : 0L;
        ps[0][J] = v;
        ps[1][J] = v;
    }

    const int n0 = seg * SEGLEN;
    const float* xbase = x + (size_t)(b0 + xb) * NSITES * FEATD + xf;

    // ---- prologue: stage XS(0); prefetch afa(site 0a); load x(pair 1) ----
    {
        float2 a = *(const float2*)(xbase + (size_t)(n0 + 0) * FEATD);
        float2 b = *(const float2*)(xbase + (size_t)(n0 + 1) * FEATD);
        int v0 = __builtin_amdgcn_cvt_pk_fp8_f32(a.x, a.y, 0, false);
        *(unsigned short*)&XS[0][0][xb * 72 + xf] = (unsigned short)(v0 & 0xffff);
        int v1 = __builtin_amdgcn_cvt_pk_fp8_f32(b.x, b.y, 0, false);
        *(unsigned short*)&XS[0][1][xb * 72 + xf] = (unsigned short)(v1 & 0xffff);
    }
    long afa[16];
    af_load(afa, core8, n0, wave, cl, q);
    float2 xa  = *(const float2*)(xbase + (size_t)(n0 + 2) * FEATD);
    float2 xbv = *(const float2*)(xbase + (size_t)(n0 + 3) * FEATD);
    __syncthreads();   // XS(0) visible

    // ---- I_-1: build pair 0 -> BUF[0]; stage XS(1); prefetch afa(1a), x(2) ----
    {
        long afb[16];
        af_load(afb, core8, n0 + 1, wave, cl, q);
        build_a(afa, &XS[0][0][0], BUF[0], wave, cl, q);
        build_b(afb, &XS[0][1][0], BUF[0] + MSIZE, wave, cl, q);
    }
    {
        int v0 = __builtin_amdgcn_cvt_pk_fp8_f32(xa.x, xa.y, 0, false);
        *(unsigned short*)&XS[1][0][xb * 72 + xf] = (unsigned short)(v0 & 0xffff);
        int v1 = __builtin_amdgcn_cvt_pk_fp8_f32(xbv.x, xbv.y, 0, false);
        *(unsigned short*)&XS[1][1][xb * 72 + xf] = (unsigned short)(v1 & 0xffff);
    }
    af_load(afa, core8, n0 + 2, wave, cl, q);   // site 1a
    xa  = *(const float2*)(xbase + (size_t)(n0 + 4) * FEATD);   // pair 2
    xbv = *(const float2*)(xbase + (size_t)(n0 + 5) * FEATD);
    __syncthreads();   // BUF[0] + XS(1) visible

    // ---- main loop: interval I_j = product(j) + build(j+1), ONE barrier ----
    for (int j = 0; j < NPAIR - 1; ++j) {
        const int jn = j + 1;
        const unsigned char* MAc = BUF[j & 1];
        const unsigned char* MBc = BUF[j & 1] + MSIZE;
        unsigned char* MAn = BUF[jn & 1];
        unsigned char* MBn = BUF[jn & 1] + MSIZE;

        // product fragment reads FIRST (heads the serial chain)
        long pa[2][2], pb[2][2];
#pragma unroll
        for (int bi = 0; bi < 2; ++bi) {
            const int bb = wave * 2 + bi;
            pa[bi][0] = ld8(MAc + bb * BSTRIDE + cl * RSTRIDE + q * 8);
            pa[bi][1] = ld8(MAc + bb * BSTRIDE + (16 + cl) * RSTRIDE + q * 8);
            pb[bi][0] = ld8(MBc + bb * BSTRIDE + cl * RSTRIDE + q * 8);
            pb[bi][1] = ld8(MBc + bb * BSTRIDE + (16 + cl) * RSTRIDE + q * 8);
        }

        // build pair j+1 into the other buffer (fills product's stall shadow)
        {
            long afb[16];
            af_load(afb, core8, n0 + 2 * jn + 1, wave, cl, q);
            build_a(afa, &XS[jn & 1][0][0], MAn, wave, cl, q);
            build_b(afb, &XS[jn & 1][1][0], MBn, wave, cl, q);
        }

        // next-next prefetch: XS(j+2) store, afa(j+2), x(j+3)
        if (j + 2 < NPAIR) {
            int v0 = __builtin_amdgcn_cvt_pk_fp8_f32(xa.x, xa.y, 0, false);
            *(unsigned short*)&XS[(j + 2) & 1][0][xb * 72 + xf] = (unsigned short)(v0 & 0xffff);
            int v1 = __builtin_amdgcn_cvt_pk_fp8_f32(xbv.x, xbv.y, 0, false);
            *(unsigned short*)&XS[(j + 2) & 1][1][xb * 72 + xf] = (unsigned short)(v1 & 0xffff);
            af_load(afa, core8, n0 + 2 * (j + 2), wave, cl, q);
            if (j + 3 < NPAIR) {
                xa  = *(const float2*)(xbase + (size_t)(n0 + 2 * (j + 3)) * FEATD);
                xbv = *(const float2*)(xbase + (size_t)(n0 + 2 * (j + 3) + 1) * FEATD);
            }
        }

        // product compute: N = M_a*M_b, then chain fold ps <- N^T * ps
#pragma unroll
        for (int bi = 0; bi < 2; ++bi) {
            float4v z00 = {0.f, 0.f, 0.f, 0.f}, z01 = {0.f, 0.f, 0.f, 0.f};
            float4v z10 = {0.f, 0.f, 0.f, 0.f}, z11 = {0.f, 0.f, 0.f, 0.f};
            z00 = __builtin_amdgcn_mfma_f32_16x16x32_fp8_fp8(pa[bi][0], pb[bi][0], z00, 0, 0, 0);
            z01 = __builtin_amdgcn_mfma_f32_16x16x32_fp8_fp8(pa[bi][0], pb[bi][1], z01, 0, 0, 0);
            z10 = __builtin_amdgcn_mfma_f32_16x16x32_fp8_fp8(pa[bi][1], pb[bi][0], z10, 0, 0, 0);
            z11 = __builtin_amdgcn_mfma_f32_16x16x32_fp8_fp8(pa[bi][1], pb[bi][1], z11, 0, 0, 0);
            long ca0 = cvt_frag(z00, z10, idxlo, idxhi, selhi);
            long ca1 = cvt_frag(z01, z11, idxlo, idxhi, selhi);
            float4v c00 = {0.f, 0.f, 0.f, 0.f}, c01 = {0.f, 0.f, 0.f, 0.f};
            float4v c10 = {0.f, 0.f, 0.f, 0.f}, c11 = {0.f, 0.f, 0.f, 0.f};
            c00 = __builtin_amdgcn_mfma_f32_16x16x32_fp8_fp8(ca0, ps[bi][0], c00, 0, 0, 0);
            c01 = __builtin_amdgcn_mfma_f32_16x16x32_fp8_fp8(ca0, ps[bi][1], c01, 0, 0, 0);
            c10 = __builtin_amdgcn_mfma_f32_16x16x32_fp8_fp8(ca1, ps[bi][0], c10, 0, 0, 0);
            c11 = __builtin_amdgcn_mfma_f32_16x16x32_fp8_fp8(ca1, ps[bi][1], c11, 0, 0, 0);
            ps[bi][0] = cvt_frag(c00, c10, idxlo, idxhi, selhi);
            ps[bi][1] = cvt_frag(c01, c11, idxlo, idxhi, selhi);
        }

        __syncthreads();   // BUF[jn&1] visible for product(j+1); XS slot handed off
    }

    // ---- final interval: product(7) only ----
    {
        const unsigned char* MAc = BUF[(NPAIR - 1) & 1];
        const unsigned char* MBc = BUF[(NPAIR - 1) & 1] + MSIZE;
#pragma unroll
        for (int bi = 0; bi < 2; ++bi) {
            const int bb = wave * 2 + bi;
            long pa0 = ld8(MAc + bb * BSTRIDE + cl * RSTRIDE + q * 8);
            long pa1 = ld8(MAc + bb * BSTRIDE + (16 + cl) * RSTRIDE + q * 8);
            long pb0 = ld8(MBc + bb * BSTRIDE + cl * RSTRIDE + q * 8);
            long pb1 = ld8(MBc + bb * BSTRIDE + (16 + cl) * RSTRIDE + q * 8);
            float4v z00 = {0.f, 0.f, 0.f, 0.f}, z01 = {0.f, 0.f, 0.f, 0.f};
            float4v z10 = {0.f, 0.f, 0.f, 0.f}, z11 = {0.f, 0.f, 0.f, 0.f};
            z00 = __builtin_amdgcn_mfma_f32_16x16x32_fp8_fp8(pa0, pb0, z00, 0, 0, 0);
            z01 = __builtin_amdgcn_mfma_f32_16x16x32_fp8_fp8(pa0, pb1, z01, 0, 0, 0);
            z10 = __builtin_amdgcn_mfma_f32_16x16x32_fp8_fp8(pa1, pb0, z10, 0, 0, 0);
            z11 = __builtin_amdgcn_mfma_f32_16x16x32_fp8_fp8(pa1, pb1, z11, 0, 0, 0);
            long ca0 = cvt_frag(z00, z10, idxlo, idxhi, selhi);
            long ca1 = cvt_frag(z01, z11, idxlo, idxhi, selhi);
            float4v c00 = {0.f, 0.f, 0.f, 0.f}, c01 = {0.f, 0.f, 0.f, 0.f};
            float4v c10 = {0.f, 0.f, 0.f, 0.f}, c11 = {0.f, 0.f, 0.f, 0.f};
            c00 = __builtin_amdgcn_mfma_f32_16x16x32_fp8_fp8(ca0, ps[bi][0], c00, 0, 0, 0);
            c01 = __builtin_amdgcn_mfma_f32_16x16x32_fp8_fp8(ca0, ps[bi][1], c01, 0, 0, 0);
            c10 = __builtin_amdgcn_mfma_f32_16x16x32_fp8_fp8(ca1, ps[bi][0], c10, 0, 0, 0);
            c11 = __builtin_amdgcn_mfma_f32_16x16x32_fp8_fp8(ca1, ps[bi][1], c11, 0, 0, 0);
            ps[bi][0] = cvt_frag(c00, c10, idxlo, idxhi, selhi);
            ps[bi][1] = cvt_frag(c01, c11, idxlo, idxhi, selhi);
        }
    }

    // ---- dump P (=16*segment product) via BUF[0], coalesced global store ----
#pragma unroll
    for (int bi = 0; bi < 2; ++bi) {
        const int bb = wave * 2 + bi;
#pragma unroll
        for (int J = 0; J < 2; ++J)
            *(long*)&BUF[0][bb * 1024 + (J * 16 + cl) * 32 + q * 8] = ps[bi][J];
    }
    __syncthreads();
    {
        const uint4* p = (const uint4*)&BUF[0][t * 32];
        uint4* g = (uint4*)(Pout + ((size_t)seg * 2048 + b0) * 1024 + (size_t)t * 32);
        g[0] = p[0];
        g[1] = p[1];
    }
}

__global__ __launch_bounds__(256)
void combine(const unsigned char* __restrict__ Pout, const float* __restrict__ startv,
             const float* __restrict__ endv, const float* __restrict__ fc_w,
             const float* __restrict__ fc_b, float* __restrict__ out) {
    __shared__ __align__(16) unsigned char st[8 * 1024];
    __shared__ float resA[8][33], resB[8][33];
    __shared__ float val[8];
    const int t  = threadIdx.x;
    const int b0 = blockIdx.x * 8;
    const int bb = t >> 5, r = t & 31;

    // hoist ALL 8 seg loads (independent -> one HBM latency, not 8 serial)
    uint4 ga[NSEG][2];
#pragma unroll
    for (int s = 0; s < NSEG; ++s) {
        const uint4* g = (const uint4*)(Pout + ((size_t)s * 2048 + b0) * 1024 + (size_t)t * 32);
        ga[s][0] = g[0];
        ga[s][1] = g[1];
    }

    resA[bb][r] = startv[r];
    for (int s = 0; s < NSEG; ++s) {
        {
            uint4* p = (uint4*)&st[t * 32];
            p[0] = ga[s][0];
            p[1] = ga[s][1];
        }
        __syncthreads();
        const float* rin = (s & 1) ? &resB[bb][0] : &resA[bb][0];
        float* rout      = (s & 1) ? &resA[bb][0] : &resB[bb][0];
        float acc = 0.f;
#pragma unroll
        for (int d = 0; d < BOND; ++d) {
            int byte = st[bb * 1024 + d * 32 + r];
            acc += rin[d] * __builtin_amdgcn_cvt_f32_fp8(byte, 0);
        }
        rout[r] = acc * 0.0625f;
        __syncthreads();
    }
    // NSEG even -> result in resA
    float prod = resA[bb][r] * endv[r];
#pragma unroll
    for (int off = 16; off >= 1; off >>= 1) prod += __shfl_down(prod, off, 32);
    if (r == 0) val[bb] = prod;
    __syncthreads();

    const float v = val[t >> 5];
    const int j0 = (t & 31) * 8;
    const int ob = b0 + (t >> 5);
#pragma unroll
    for (int i = 0; i < 2; ++i) {
        int j = j0 + i * 4;
        float4 w4 = *(const float4*)(fc_w + j);
        float4 bbv = *(const float4*)(fc_b + j);
        float4 o;
        o.x = v * w4.x + bbv.x;
        o.y = v * w4.y + bbv.y;
        o.z = v * w4.z + bbv.z;
        o.w = v * w4.w + bbv.w;
        *(float4*)(out + (size_t)ob * OUTD + j) = o;
    }
}

extern "C" void kernel_launch(void* const* d_in, const int* in_sizes, int n_in,
                              void* d_out, int out_size, void* d_ws, size_t ws_size,
                              hipStream_t stream) {
    const float* x      = (const float*)d_in[0];
    const float* cores  = (const float*)d_in[1];
    const float* startv = (const float*)d_in[2];
    const float* endv   = (const float*)d_in[3];
    const float* fc_w   = (const float*)d_in[4];
    const float* fc_b   = (const float*)d_in[5];
    float* out = (float*)d_out;

    unsigned char* core8 = (unsigned char*)d_ws;                       // 8.4 MB
    unsigned char* Pout  = core8 + (size_t)NSITES * 1024 * FEATD;      // 16.8 MB

    prep_cores8<<<NSITES * BOND, 256, 0, stream>>>(cores, core8);
    mps_seg<<<dim3(NSEG, NBT), 512, 0, stream>>>(x, core8, Pout);
    combine<<<2048 / 8, 256, 0, stream>>>(Pout, startv, endv, fc_w, fc_b, out);
}